// Round 3
// baseline (320.166 us; speedup 1.0000x reference)
//
#include <hip/hip_runtime.h>
#include <math.h>

#define N 512
#define NN (N * N)
#define C 16
#define K 262144
#define LOG2N 9

// skewed LDS addressing (float4-element units): +1 every 16 elements.
// Makes bit-reversed scatter writes and stride-2^s butterfly b128 accesses
// hit the LDS bank floor instead of 8-16-way conflicts.
#define SK(e) ((e) + ((e) >> 4))
#define LROW 544   // 512 + 32 skew slack

// ============ fused front-end: hist + scan + place-offsets, ONE kernel ============
// 256 blocks x 256 threads: trivially all-resident (1 block/CU floor), so a
// device-scope atomic grid barrier is deadlock-free. count+bar pre-zeroed by
// the single memset node.

__device__ __forceinline__ void gridbar(int* bar, int target) {
    __syncthreads();
    if (threadIdx.x == 0) {
        __threadfence();
        __hip_atomic_fetch_add(bar, 1, __ATOMIC_ACQ_REL, __HIP_MEMORY_SCOPE_AGENT);
        while (__hip_atomic_load(bar, __ATOMIC_ACQUIRE, __HIP_MEMORY_SCOPE_AGENT) < target) {
            __builtin_amdgcn_s_sleep(8);
        }
        __threadfence();
    }
    __syncthreads();
}

__global__ __launch_bounds__(256) void scan_all_kernel(const float2* __restrict__ traj,
                                                       const float* __restrict__ dcf,
                                                       int* __restrict__ cell,
                                                       float* __restrict__ sdcf,
                                                       int* __restrict__ count,
                                                       int* __restrict__ offs,
                                                       int* __restrict__ cursor,
                                                       int* __restrict__ chunk_sum,
                                                       int* __restrict__ bar) {
    __shared__ int sd[256];
    int t = threadIdx.x;
    int b = blockIdx.x;

    // ---- phase A: histogram + per-point cell/sdcf (count pre-zeroed) ----
    for (int i = b * 256 + t; i < K; i += 256 * 256) {
        float2 tr = traj[i];
        int iy = __float2int_rn((tr.x + 0.5f) * (float)N) & (N - 1);
        int ix = __float2int_rn((tr.y + 0.5f) * (float)N) & (N - 1);
        int cl = iy * N + ix;
        cell[i] = cl;
        float s = ((iy + ix) & 1) ? -1.0f : 1.0f;   // ifftshift folded into sign
        sdcf[i] = dcf[i] * s;
        atomicAdd(&count[cl], 1);
    }
    gridbar(bar, 256);

    // ---- phase B: local scan of this block's 1024 cells (4 per thread) ----
    int4 c4 = ((const int4*)count)[b * 256 + t];
    int tsum = c4.x + c4.y + c4.z + c4.w;
    sd[t] = tsum;
    __syncthreads();
    for (int d = 1; d < 256; d <<= 1) {
        int tmp = (t >= d) ? sd[t - d] : 0;
        __syncthreads();
        sd[t] += tmp;
        __syncthreads();
    }
    int incl = sd[t];
    int epre = incl - tsum;              // exclusive prefix within block
    if (t == 255) chunk_sum[b] = incl;   // block total
    gridbar(bar, 512);

    // ---- phase C: lookback base + write offs/cursor ----
    __syncthreads();
    sd[t] = (t < 256) ? chunk_sum[t] : 0;
    __syncthreads();
    int gbase = 0;
    for (int j = 0; j < b; ++j) gbase += sd[j];
    int base = gbase + epre;
    int4 o;
    o.x = base;
    o.y = base + c4.x;
    o.z = base + c4.x + c4.y;
    o.w = base + c4.x + c4.y + c4.z;
    ((int4*)offs)[b * 256 + t] = o;
    ((int4*)cursor)[b * 256 + t] = o;
    if (b == 255 && t == 255) offs[NN] = K;
}

// ============ payload build: transpose x to sorted point order ============
// Reads x COALESCED, transposes 256pt x 16ch tiles through LDS, writes ONE
// 128-B all-channel chunk per point at the cursor-claimed sorted slot.
__global__ __launch_bounds__(256) void payload_kernel(const float* __restrict__ xr,
                                                      const float* __restrict__ xi,
                                                      const int* __restrict__ cell,
                                                      const float* __restrict__ sdcf,
                                                      int* __restrict__ cursor,
                                                      float2* __restrict__ pay) {
    __shared__ float tR[256][17];   // [point][channel], +1 pad -> conflict-free
    __shared__ float tI[256][17];
    __shared__ int   sp[256];
    __shared__ float sw[256];
    int t = threadIdx.x;
    int k0 = blockIdx.x * 256;
#pragma unroll
    for (int c = 0; c < C; ++c) {
        tR[t][c] = xr[(size_t)c * K + k0 + t];   // coalesced 1-KB reads
        tI[t][c] = xi[(size_t)c * K + k0 + t];
    }
    int cl = cell[k0 + t];
    float w = sdcf[k0 + t];
    sp[t] = atomicAdd(&cursor[cl], 1);           // unique sorted slot
    sw[t] = w;
    __syncthreads();
    int sg = t >> 4, l = t & 15;                 // 16 subgroups of 16 lanes
    for (int j = sg; j < 256; j += 16) {
        int pp = sp[j];
        float ww = sw[j];
        // 16 lanes write one contiguous 128-B chunk (full HBM granule)
        pay[(size_t)pp * 16 + l] = make_float2(tR[j][l] * ww, tI[j][l] * ww);
    }
}

// ============ fused grid-build + row FFT: atomic-free, barrier-free ============
// block = (row r, channel-half h), 4 waves. Wave w owns channel-quad q=h*4+w
// (channels 2q,2q+1) in a private float4 LDS stripe. Gather is CELL-parallel:
// all 8 first-point loads issued up-front (in-flight together), rare >1-point
// tails after. One plain ds_write_b128 per cell. FFT wave-local via
// s_waitcnt lgkmcnt(0). ZERO __syncthreads.
__global__ __launch_bounds__(256) void build8_kernel(const int* __restrict__ offs,
                                                     const float4* __restrict__ pay4,
                                                     float2* __restrict__ grid) {
    __shared__ float4 lds[4][LROW];   // 34.8 KB
    int bid = blockIdx.x;
    int h = bid & 1;
    int r = bid >> 1;
    int t = threadIdx.x;
    int w = t >> 6;
    int l = t & 63;
    int q = h * 4 + w;                // float4 chunk -> channels 2q, 2q+1
    const int* ro = offs + r * N;

    int sv[8], ev[8];
#pragma unroll
    for (int it = 0; it < 8; ++it) {
        int col = l + (it << 6);
        sv[it] = ro[col];
        ev[it] = ro[col + 1];         // col=511,r=511 reads offs[NN]=K
    }
    float4 vv[8];
#pragma unroll
    for (int it = 0; it < 8; ++it) {  // 8 independent first-point loads in flight
        vv[it] = make_float4(0.f, 0.f, 0.f, 0.f);
        if (sv[it] < ev[it]) vv[it] = pay4[(size_t)sv[it] * 8 + q];
    }
#pragma unroll
    for (int it = 0; it < 8; ++it) {
        float4 acc = vv[it];
        for (int p = sv[it] + 1; p < ev[it]; ++p) {   // rare tail (P(>=2) ~ 26%)
            float4 v2 = pay4[(size_t)p * 8 + q];
            acc.x += v2.x; acc.y += v2.y; acc.z += v2.z; acc.w += v2.w;
        }
        int col = l + (it << 6);
        int bc = (int)(__brev((unsigned)col) >> (32 - LOG2N));   // bit-reversed col
        lds[w][SK(bc)] = acc;
    }
    asm volatile("s_waitcnt lgkmcnt(0)" ::: "memory");

    // ---- 9 radix-2 DIT stages, +i exponent, wave-local ----
    for (int s = 1; s <= LOG2N; ++s) {
        int half = 1 << (s - 1);
        int m = half << 1;
#pragma unroll
        for (int i = 0; i < 4; ++i) {          // 256 butterflies / 64 lanes
            int b2 = l + (i << 6);
            int j = b2 & (half - 1);
            int grp = b2 >> (s - 1);
            int p1 = grp * m + j;
            int p2 = p1 + half;
            float ang = 6.283185307179586f * (float)j / (float)m;
            float sn, cs;
            __sincosf(ang, &sn, &cs);
            float4 v = lds[w][SK(p2)];
            float4 u = lds[w][SK(p1)];
            float tr0 = cs * v.x - sn * v.y;
            float ti0 = cs * v.y + sn * v.x;
            float tr1 = cs * v.z - sn * v.w;
            float ti1 = cs * v.w + sn * v.z;
            lds[w][SK(p2)] = make_float4(u.x - tr0, u.y - ti0, u.z - tr1, u.w - ti1);
            lds[w][SK(p1)] = make_float4(u.x + tr0, u.y + ti0, u.z + tr1, u.w + ti1);
        }
        asm volatile("s_waitcnt lgkmcnt(0)" ::: "memory");
    }

    // ---- store this wave's 2 channels, coalesced ----
    int c0 = q * 2;
    float2* g0 = grid + (size_t)c0 * NN + (size_t)r * N;
    float2* g1 = grid + (size_t)(c0 + 1) * NN + (size_t)r * N;
    for (int i = l; i < N; i += 64) {
        float4 v = lds[w][SK(i)];
        g0[i] = make_float2(v.x, v.y);
        g1[i] = make_float2(v.z, v.w);
    }
}

// ============ fused column FFT + combine ============
// block = column pair (cols 2cp, 2cp+1), 256 blocks. Wave w serially handles
// channels {w, w+4, w+8, w+12}: scatter-load column (bit-reversed) into its
// private float4 stripe, wave-local FFT (same as build8), then accumulate
// conj(csm)*img into 8 registers/lane. End: cross-wave LDS reduce + signed
// store to out. Saves the 64-MB grid round trip entirely.
__global__ __launch_bounds__(256) void colfft_combine_kernel(const float2* __restrict__ grid,
                                                             const float* __restrict__ csr,
                                                             const float* __restrict__ csi,
                                                             float* __restrict__ out) {
    __shared__ float4 lds[4][LROW];   // 34.8 KB
    int cp = blockIdx.x;              // cols 2cp, 2cp+1
    int t = threadIdx.x;
    int w = t >> 6;
    int l = t & 63;
    int colb = cp * 2;

    float4 acc[8];
#pragma unroll
    for (int j = 0; j < 8; ++j) acc[j] = make_float4(0.f, 0.f, 0.f, 0.f);

    for (int ci = 0; ci < 4; ++ci) {
        int c = w + ci * 4;           // wave w: channels w, w+4, w+8, w+12
        const float2* g = grid + (size_t)c * NN + colb;
        // load 8 rows/lane (16-B requests), scatter bit-reversed into stripe
#pragma unroll
        for (int j = 0; j < 8; ++j) {
            int row = l + (j << 6);
            float2 a = g[(size_t)row * N];
            float2 bv = g[(size_t)row * N + 1];
            int br = (int)(__brev((unsigned)row) >> (32 - LOG2N));
            lds[w][SK(br)] = make_float4(a.x, a.y, bv.x, bv.y);
        }
        asm volatile("s_waitcnt lgkmcnt(0)" ::: "memory");

        // 9-stage wave-local FFT (2 complex per float4, shared twiddle)
        for (int s = 1; s <= LOG2N; ++s) {
            int half = 1 << (s - 1);
            int m = half << 1;
#pragma unroll
            for (int i = 0; i < 4; ++i) {
                int b2 = l + (i << 6);
                int j = b2 & (half - 1);
                int grp = b2 >> (s - 1);
                int p1 = grp * m + j;
                int p2 = p1 + half;
                float ang = 6.283185307179586f * (float)j / (float)m;
                float sn, cs;
                __sincosf(ang, &sn, &cs);
                float4 v = lds[w][SK(p2)];
                float4 u = lds[w][SK(p1)];
                float tr0 = cs * v.x - sn * v.y;
                float ti0 = cs * v.y + sn * v.x;
                float tr1 = cs * v.z - sn * v.w;
                float ti1 = cs * v.w + sn * v.z;
                lds[w][SK(p2)] = make_float4(u.x - tr0, u.y - ti0, u.z - tr1, u.w - ti1);
                lds[w][SK(p1)] = make_float4(u.x + tr0, u.y + ti0, u.z + tr1, u.w + ti1);
            }
            asm volatile("s_waitcnt lgkmcnt(0)" ::: "memory");
        }

        // accumulate conj(csm)*img for this channel into registers
        const float* cr = csr + (size_t)c * NN + colb;
        const float* cim = csi + (size_t)c * NN + colb;
#pragma unroll
        for (int j = 0; j < 8; ++j) {
            int row = l + (j << 6);
            float4 v = lds[w][SK(row)];
            float2 a2 = *(const float2*)(cr + (size_t)row * N);
            float2 b2 = *(const float2*)(cim + (size_t)row * N);
            acc[j].x += a2.x * v.x + b2.x * v.y;   // re col0
            acc[j].y += a2.x * v.y - b2.x * v.x;   // im col0
            acc[j].z += a2.y * v.z + b2.y * v.w;   // re col1
            acc[j].w += a2.y * v.w - b2.y * v.z;   // im col1
        }
        asm volatile("s_waitcnt lgkmcnt(0)" ::: "memory");  // stripe reads done before next overwrite
    }

    // ---- cross-wave reduce into stripe 0, then signed store ----
    __syncthreads();
    for (int ww = 0; ww < 4; ++ww) {
        if (w == ww) {
#pragma unroll
            for (int j = 0; j < 8; ++j) {
                int row = l + (j << 6);
                if (ww == 0) {
                    lds[0][SK(row)] = acc[j];
                } else {
                    float4 u = lds[0][SK(row)];
                    u.x += acc[j].x; u.y += acc[j].y; u.z += acc[j].z; u.w += acc[j].w;
                    lds[0][SK(row)] = u;
                }
            }
        }
        __syncthreads();
    }
    for (int row = t; row < N; row += 256) {
        float4 v = lds[0][SK(row)];
        float s0 = ((row + colb) & 1) ? -1.f : 1.f;   // fftshift sign, col0
        float s1 = -s0;                                // col1 parity flips
        *(float2*)(out + (size_t)row * N + colb)      = make_float2(s0 * v.x, s1 * v.z);
        *(float2*)(out + NN + (size_t)row * N + colb) = make_float2(s0 * v.y, s1 * v.w);
    }
}

extern "C" void kernel_launch(void* const* d_in, const int* in_sizes, int n_in,
                              void* d_out, int out_size, void* d_ws, size_t ws_size,
                              hipStream_t stream) {
    const float* x_real   = (const float*)d_in[0];
    const float* x_imag   = (const float*)d_in[1];
    const float* csm_real = (const float*)d_in[2];
    const float* csm_imag = (const float*)d_in[3];
    const float2* traj    = (const float2*)d_in[4];
    const float* dcf      = (const float*)d_in[5];
    float* out = (float*)d_out;

    char* ws = (char*)d_ws;
    size_t o = 0;
    float* grid  = (float*)(ws + o); o += (size_t)C * NN * 2 * sizeof(float);  // 32 MB
    int*   cell  = (int*)(ws + o);   o += (size_t)K * sizeof(int);             // 1 MB
    float* sdcf  = (float*)(ws + o); o += (size_t)K * sizeof(float);           // 1 MB
    int*   count = (int*)(ws + o);   o += (size_t)NN * sizeof(int);            // 1 MB
    int*   bar   = (int*)(ws + o);   o += 64;                                  // zeroed with count
    int*   offs  = (int*)(ws + o);   o += ((size_t)NN + 4) * sizeof(int);      // 1 MB (+pad)
    int*   cursor= (int*)(ws + o);   o += (size_t)NN * sizeof(int);            // 1 MB
    float2* pay  = (float2*)(ws + o); o += (size_t)K * 16 * sizeof(float2);    // 32 MB
    int*   chunk_sum = (int*)(ws + o); o += 256 * sizeof(int);

    // one memset zeroes count AND the grid-barrier counter
    (void)hipMemsetAsync(count, 0, (size_t)NN * sizeof(int) + 64, stream);

    scan_all_kernel<<<256, 256, 0, stream>>>(traj, dcf, cell, sdcf, count, offs, cursor, chunk_sum, bar);
    payload_kernel<<<K / 256, 256, 0, stream>>>(x_real, x_imag, cell, sdcf, cursor, pay);
    build8_kernel<<<N * 2, 256, 0, stream>>>(offs, (const float4*)pay, (float2*)grid);
    colfft_combine_kernel<<<256, 256, 0, stream>>>((const float2*)grid, csm_real, csm_imag, out);
}

// Round 4
// 261.867 us; speedup vs baseline: 1.2226x; 1.2226x over previous
//
#include <hip/hip_runtime.h>
#include <math.h>

#define N 512
#define NN (N * N)
#define C 16
#define K 262144
#define LOG2N 9
#define NCOL 8

// skewed LDS addressing (float4-element units): +1 every 16 elements.
#define SK(e) ((e) + ((e) >> 4))
#define LROW 544   // 512 + 32 skew slack

// ============ fused front-end: hist + scan + place-offsets, ONE kernel ============
// 256 blocks x 256 threads: trivially all-resident (1 block/CU floor), so a
// device-scope atomic grid barrier is deadlock-free. count+bar pre-zeroed by
// the single memset node.

__device__ __forceinline__ void gridbar(int* bar, int target) {
    __syncthreads();
    if (threadIdx.x == 0) {
        __threadfence();
        __hip_atomic_fetch_add(bar, 1, __ATOMIC_ACQ_REL, __HIP_MEMORY_SCOPE_AGENT);
        while (__hip_atomic_load(bar, __ATOMIC_ACQUIRE, __HIP_MEMORY_SCOPE_AGENT) < target) {
            __builtin_amdgcn_s_sleep(8);
        }
        __threadfence();
    }
    __syncthreads();
}

__global__ __launch_bounds__(256) void scan_all_kernel(const float2* __restrict__ traj,
                                                       const float* __restrict__ dcf,
                                                       int* __restrict__ cell,
                                                       float* __restrict__ sdcf,
                                                       int* __restrict__ count,
                                                       int* __restrict__ offs,
                                                       int* __restrict__ cursor,
                                                       int* __restrict__ chunk_sum,
                                                       int* __restrict__ bar) {
    __shared__ int sd[256];
    int t = threadIdx.x;
    int b = blockIdx.x;

    // ---- phase A: histogram + per-point cell/sdcf (count pre-zeroed) ----
    for (int i = b * 256 + t; i < K; i += 256 * 256) {
        float2 tr = traj[i];
        int iy = __float2int_rn((tr.x + 0.5f) * (float)N) & (N - 1);
        int ix = __float2int_rn((tr.y + 0.5f) * (float)N) & (N - 1);
        int cl = iy * N + ix;
        cell[i] = cl;
        float s = ((iy + ix) & 1) ? -1.0f : 1.0f;   // ifftshift folded into sign
        sdcf[i] = dcf[i] * s;
        atomicAdd(&count[cl], 1);
    }
    gridbar(bar, 256);

    // ---- phase B: local scan of this block's 1024 cells (4 per thread) ----
    int4 c4 = ((const int4*)count)[b * 256 + t];
    int tsum = c4.x + c4.y + c4.z + c4.w;
    sd[t] = tsum;
    __syncthreads();
    for (int d = 1; d < 256; d <<= 1) {
        int tmp = (t >= d) ? sd[t - d] : 0;
        __syncthreads();
        sd[t] += tmp;
        __syncthreads();
    }
    int incl = sd[t];
    int epre = incl - tsum;              // exclusive prefix within block
    if (t == 255) chunk_sum[b] = incl;   // block total
    gridbar(bar, 512);

    // ---- phase C: lookback base + write offs/cursor ----
    __syncthreads();
    sd[t] = chunk_sum[t];
    __syncthreads();
    int gbase = 0;
    for (int j = 0; j < b; ++j) gbase += sd[j];
    int base = gbase + epre;
    int4 o;
    o.x = base;
    o.y = base + c4.x;
    o.z = base + c4.x + c4.y;
    o.w = base + c4.x + c4.y + c4.z;
    ((int4*)offs)[b * 256 + t] = o;
    ((int4*)cursor)[b * 256 + t] = o;
    if (b == 255 && t == 255) offs[NN] = K;
}

// ============ payload build: transpose x to sorted point order ============
__global__ __launch_bounds__(256) void payload_kernel(const float* __restrict__ xr,
                                                      const float* __restrict__ xi,
                                                      const int* __restrict__ cell,
                                                      const float* __restrict__ sdcf,
                                                      int* __restrict__ cursor,
                                                      float2* __restrict__ pay) {
    __shared__ float tR[256][17];   // [point][channel], +1 pad -> conflict-free
    __shared__ float tI[256][17];
    __shared__ int   sp[256];
    __shared__ float sw[256];
    int t = threadIdx.x;
    int k0 = blockIdx.x * 256;
#pragma unroll
    for (int c = 0; c < C; ++c) {
        tR[t][c] = xr[(size_t)c * K + k0 + t];   // coalesced 1-KB reads
        tI[t][c] = xi[(size_t)c * K + k0 + t];
    }
    int cl = cell[k0 + t];
    float w = sdcf[k0 + t];
    sp[t] = atomicAdd(&cursor[cl], 1);           // unique sorted slot
    sw[t] = w;
    __syncthreads();
    int sg = t >> 4, l = t & 15;                 // 16 subgroups of 16 lanes
    for (int j = sg; j < 256; j += 16) {
        int pp = sp[j];
        float ww = sw[j];
        // 16 lanes write one contiguous 128-B chunk (full HBM granule)
        pay[(size_t)pp * 16 + l] = make_float2(tR[j][l] * ww, tI[j][l] * ww);
    }
}

// ============ fused grid-build + row FFT: atomic-free, barrier-free ============
__global__ __launch_bounds__(256) void build8_kernel(const int* __restrict__ offs,
                                                     const float4* __restrict__ pay4,
                                                     float2* __restrict__ grid) {
    __shared__ float4 lds[4][LROW];   // 34.8 KB
    int bid = blockIdx.x;
    int h = bid & 1;
    int r = bid >> 1;
    int t = threadIdx.x;
    int w = t >> 6;
    int l = t & 63;
    int q = h * 4 + w;                // float4 chunk -> channels 2q, 2q+1
    const int* ro = offs + r * N;

    int sv[8], ev[8];
#pragma unroll
    for (int it = 0; it < 8; ++it) {
        int col = l + (it << 6);
        sv[it] = ro[col];
        ev[it] = ro[col + 1];         // col=511,r=511 reads offs[NN]=K
    }
    float4 vv[8];
#pragma unroll
    for (int it = 0; it < 8; ++it) {  // 8 independent first-point loads in flight
        vv[it] = make_float4(0.f, 0.f, 0.f, 0.f);
        if (sv[it] < ev[it]) vv[it] = pay4[(size_t)sv[it] * 8 + q];
    }
#pragma unroll
    for (int it = 0; it < 8; ++it) {
        float4 acc = vv[it];
        for (int p = sv[it] + 1; p < ev[it]; ++p) {   // rare tail
            float4 v2 = pay4[(size_t)p * 8 + q];
            acc.x += v2.x; acc.y += v2.y; acc.z += v2.z; acc.w += v2.w;
        }
        int col = l + (it << 6);
        int bc = (int)(__brev((unsigned)col) >> (32 - LOG2N));   // bit-reversed col
        lds[w][SK(bc)] = acc;
    }
    asm volatile("s_waitcnt lgkmcnt(0)" ::: "memory");

    // ---- 9 radix-2 DIT stages, +i exponent, wave-local ----
    for (int s = 1; s <= LOG2N; ++s) {
        int half = 1 << (s - 1);
        int m = half << 1;
#pragma unroll
        for (int i = 0; i < 4; ++i) {          // 256 butterflies / 64 lanes
            int b2 = l + (i << 6);
            int j = b2 & (half - 1);
            int grp = b2 >> (s - 1);
            int p1 = grp * m + j;
            int p2 = p1 + half;
            float ang = 6.283185307179586f * (float)j / (float)m;
            float sn, cs;
            __sincosf(ang, &sn, &cs);
            float4 v = lds[w][SK(p2)];
            float4 u = lds[w][SK(p1)];
            float tr0 = cs * v.x - sn * v.y;
            float ti0 = cs * v.y + sn * v.x;
            float tr1 = cs * v.z - sn * v.w;
            float ti1 = cs * v.w + sn * v.z;
            lds[w][SK(p2)] = make_float4(u.x - tr0, u.y - ti0, u.z - tr1, u.w - ti1);
            lds[w][SK(p1)] = make_float4(u.x + tr0, u.y + ti0, u.z + tr1, u.w + ti1);
        }
        asm volatile("s_waitcnt lgkmcnt(0)" ::: "memory");
    }

    // ---- store this wave's 2 channels, coalesced ----
    int c0 = q * 2;
    float2* g0 = grid + (size_t)c0 * NN + (size_t)r * N;
    float2* g1 = grid + (size_t)(c0 + 1) * NN + (size_t)r * N;
    for (int i = l; i < N; i += 64) {
        float4 v = lds[w][SK(i)];
        g0[i] = make_float2(v.x, v.y);
        g1[i] = make_float2(v.z, v.w);
    }
}

// ============ column FFT: NCOL columns per block through LDS (round-2 proven) ============
__global__ __launch_bounds__(256) void colfft_kernel(float2* __restrict__ grid) {
    __shared__ float sr[N * NCOL];
    __shared__ float si[N * NCOL];
    int blk = blockIdx.x;                        // c * (N/NCOL) + cg
    int c = blk >> 6;
    int cg = blk & 63;
    float2* base = grid + (size_t)c * NN + cg * NCOL;
    int t = threadIdx.x;

    for (int e = t; e < N * NCOL; e += 256) {
        int row = e >> 3, col = e & 7;
        float2 v = base[(size_t)row * N + col];
        sr[e] = v.x; si[e] = v.y;
    }
    __syncthreads();

    int col = t & 7;
    int tg = t >> 3;
    for (int i = tg; i < N; i += 32) {
        int j = __brev((unsigned)i) >> (32 - LOG2N);
        if (j > i) {
            int a1 = i * NCOL + col, a2 = j * NCOL + col;
            float a = sr[a1]; sr[a1] = sr[a2]; sr[a2] = a;
            float b = si[a1]; si[a1] = si[a2]; si[a2] = b;
        }
    }
    __syncthreads();

    for (int s = 1; s <= LOG2N; ++s) {
        int half = 1 << (s - 1);
        int m = half << 1;
        for (int b = tg; b < 256; b += 32) {
            int j = b & (half - 1);
            int grp = b >> (s - 1);
            int p1 = grp * m + j;
            int p2 = p1 + half;
            float ang = 6.283185307179586f * (float)j / (float)m;
            float sn, cs;
            __sincosf(ang, &sn, &cs);
            int a1 = p1 * NCOL + col, a2 = p2 * NCOL + col;
            float xr2 = sr[a2], xi2 = si[a2];
            float tr = cs * xr2 - sn * xi2;
            float ti = cs * xi2 + sn * xr2;
            float ur = sr[a1], ui = si[a1];
            sr[a2] = ur - tr; si[a2] = ui - ti;
            sr[a1] = ur + tr; si[a1] = ui + ti;
        }
        __syncthreads();
    }

    for (int e = t; e < N * NCOL; e += 256) {
        int row = e >> 3, col2 = e & 7;
        base[(size_t)row * N + col2] = make_float2(sr[e], si[e]);
    }
}

// ============ combine: out = (-1)^(ny+nx) * sum_c conj(csm)*img (round-2 proven) ============
__global__ __launch_bounds__(256) void combine_kernel(const float* __restrict__ csr,
                                                      const float* __restrict__ csi,
                                                      const float2* __restrict__ grid,
                                                      float* __restrict__ out) {
    int pix = blockIdx.x * 256 + threadIdx.x;
    int ny = pix >> LOG2N, nx = pix & (N - 1);
    float ar = 0.f, ai = 0.f;
#pragma unroll
    for (int c = 0; c < C; ++c) {
        float2 uv = grid[(size_t)c * NN + pix];
        float a = csr[c * NN + pix];
        float b = csi[c * NN + pix];
        ar += a * uv.x + b * uv.y;
        ai += a * uv.y - b * uv.x;
    }
    float s = ((ny + nx) & 1) ? -1.f : 1.f;      // fftshift folded into output sign
    out[pix] = s * ar;
    out[NN + pix] = s * ai;
}

extern "C" void kernel_launch(void* const* d_in, const int* in_sizes, int n_in,
                              void* d_out, int out_size, void* d_ws, size_t ws_size,
                              hipStream_t stream) {
    const float* x_real   = (const float*)d_in[0];
    const float* x_imag   = (const float*)d_in[1];
    const float* csm_real = (const float*)d_in[2];
    const float* csm_imag = (const float*)d_in[3];
    const float2* traj    = (const float2*)d_in[4];
    const float* dcf      = (const float*)d_in[5];
    float* out = (float*)d_out;

    char* ws = (char*)d_ws;
    size_t o = 0;
    float* grid  = (float*)(ws + o); o += (size_t)C * NN * 2 * sizeof(float);  // 32 MB
    int*   cell  = (int*)(ws + o);   o += (size_t)K * sizeof(int);             // 1 MB
    float* sdcf  = (float*)(ws + o); o += (size_t)K * sizeof(float);           // 1 MB
    int*   count = (int*)(ws + o);   o += (size_t)NN * sizeof(int);            // 1 MB
    int*   bar   = (int*)(ws + o);   o += 64;                                  // zeroed with count
    int*   offs  = (int*)(ws + o);   o += ((size_t)NN + 4) * sizeof(int);      // 1 MB (+pad)
    int*   cursor= (int*)(ws + o);   o += (size_t)NN * sizeof(int);            // 1 MB
    float2* pay  = (float2*)(ws + o); o += (size_t)K * 16 * sizeof(float2);    // 32 MB
    int*   chunk_sum = (int*)(ws + o); o += 256 * sizeof(int);

    // one memset zeroes count AND the grid-barrier counter
    (void)hipMemsetAsync(count, 0, (size_t)NN * sizeof(int) + 64, stream);

    scan_all_kernel<<<256, 256, 0, stream>>>(traj, dcf, cell, sdcf, count, offs, cursor, chunk_sum, bar);
    payload_kernel<<<K / 256, 256, 0, stream>>>(x_real, x_imag, cell, sdcf, cursor, pay);
    build8_kernel<<<N * 2, 256, 0, stream>>>(offs, (const float4*)pay, (float2*)grid);
    colfft_kernel<<<C * (N / NCOL), 256, 0, stream>>>((float2*)grid);
    combine_kernel<<<NN / 256, 256, 0, stream>>>(csm_real, csm_imag, (float2*)grid, out);
}